// Round 1
// baseline (330.318 us; speedup 1.0000x reference)
//
#include <hip/hip_runtime.h>

// SCVC: out[n,o,i,j] = sum_{c,d} x[n,c,i] y[n,d,j] Cr[o,c,d]
//                      + a[n,o,i] + b[n,o,j] + bias[o]
// a = dilated conv (k=2, pad=1, dil=2) of channel-tiled x, W_A folded over the
// tile-repeat; b likewise for y / W_B.
// N=32, IN1=IN2=4, OUT=128, DX=DY=128. All float32.
//
// Store-bandwidth-bound: 256 MB out vs ~400 KB in.
// R1 restructure: one block per (n, o-PAIR) -> grid 2048 = exactly 8 blocks/CU
// (single co-resident batch, no inter-batch pipeline drain), 128 KB of stores
// per prologue instead of 64 KB, x/y loads + yr register tile shared across
// both o values. Wave store instr still covers 2 adjacent rows = dense 1 KB.

__global__ __launch_bounds__(256, 8) void scvc_kernel(
    const float* __restrict__ x,     // [32,4,128]
    const float* __restrict__ y,     // [32,4,128]
    const float* __restrict__ C,     // [128,16]
    const float* __restrict__ WA,    // [128,16,2]
    const float* __restrict__ WB,    // [128,16,2]
    const float* __restrict__ bias,  // [128]
    float* __restrict__ out)         // [32,128,128,128]
{
    const int n   = blockIdx.x >> 6;    // 0..31
    const int og  = blockIdx.x & 63;    // 0..63
    const int o0  = og << 1;            // first of the o-pair
    const int tid = threadIdx.x;

    __shared__ float csh[2][16];        // Cr[c*4+d] per oi
    __shared__ float wash[2][8];        // folded W_A: [c*2+k]
    __shared__ float wbsh[2][8];        // folded W_B: [c*2+k]
    __shared__ float t4[2][128][4];     // t4[oi][i][d] = sum_c x[c,i]*Cr[c,d]
    __shared__ float arow[2][128];
    __shared__ float bcol[2][128];      // includes bias

    const float* xb = x + n * 512;
    const float* yb = y + n * 512;

    // ---- phase 0: fold weights into LDS (64 threads, 32 per o) ----
    if (tid < 64) {
        const int oi = tid >> 5;        // which o of the pair
        const int o  = o0 + oi;
        const int t  = tid & 31;
        if (t < 16) {
            csh[oi][t] = C[o * 16 + t];
        } else if (t < 24) {
            const int idx = t - 16;             // c*2 + k
            const int c = idx >> 1, k = idx & 1;
            float s = 0.f;
            #pragma unroll
            for (int r = 0; r < 4; ++r) s += WA[o * 32 + (4 * r + c) * 2 + k];
            wash[oi][idx] = s;
        } else {
            const int idx = t - 24;
            const int c = idx >> 1, k = idx & 1;
            float s = 0.f;
            #pragma unroll
            for (int r = 0; r < 4; ++r) s += WB[o * 32 + (4 * r + c) * 2 + k];
            wbsh[oi][idx] = s;
        }
    }
    __syncthreads();

    // ---- phase 1: rows (threads 0..127) / cols (128..255), both o's ----
    if (tid < 128) {
        const int i = tid;
        float xv[4], xm[4], xp[4];
        #pragma unroll
        for (int c = 0; c < 4; ++c) {
            xv[c] = xb[c * 128 + i];
            xm[c] = (i > 0)   ? xb[c * 128 + i - 1] : 0.f;  // conv tap t-1
            xp[c] = (i < 127) ? xb[c * 128 + i + 1] : 0.f;  // conv tap t+1
        }
        #pragma unroll
        for (int oi = 0; oi < 2; ++oi) {
            #pragma unroll
            for (int d = 0; d < 4; ++d) {
                float s = 0.f;
                #pragma unroll
                for (int c = 0; c < 4; ++c) s += xv[c] * csh[oi][c * 4 + d];
                t4[oi][i][d] = s;
            }
            float a = 0.f;
            #pragma unroll
            for (int c = 0; c < 4; ++c)
                a += xm[c] * wash[oi][c * 2] + xp[c] * wash[oi][c * 2 + 1];
            arow[oi][i] = a;
        }
    } else {
        const int j = tid - 128;
        float ym[4], yp[4];
        #pragma unroll
        for (int c = 0; c < 4; ++c) {
            ym[c] = (j > 0)   ? yb[c * 128 + j - 1] : 0.f;
            yp[c] = (j < 127) ? yb[c * 128 + j + 1] : 0.f;
        }
        #pragma unroll
        for (int oi = 0; oi < 2; ++oi) {
            float b = bias[o0 + oi];
            #pragma unroll
            for (int c = 0; c < 4; ++c)
                b += ym[c] * wbsh[oi][c * 2] + yp[c] * wbsh[oi][c * 2 + 1];
            bcol[oi][j] = b;
        }
    }
    __syncthreads();

    // ---- phase 2: thread owns 4 consecutive cols; 32 threads cover a row.
    // Wave = 2 adjacent rows per store instr -> fully dense 1 KB stores.
    // Both o's of the pair streamed back-to-back, reusing yr registers.
    const int col4 = (tid & 31) * 4;   // 0,4,...,124
    const int rgrp = tid >> 5;         // 0..7

    float yr[4][4];
    #pragma unroll
    for (int d = 0; d < 4; ++d) {
        const float4 v = *(const float4*)(yb + d * 128 + col4);
        yr[d][0] = v.x; yr[d][1] = v.y; yr[d][2] = v.z; yr[d][3] = v.w;
    }

    for (int oi = 0; oi < 2; ++oi) {
        const float4 bv = *(const float4*)(&bcol[oi][col4]);  // one ds_read_b128
        float bj[4];
        bj[0] = bv.x; bj[1] = bv.y; bj[2] = bv.z; bj[3] = bv.w;

        float* op = out + (((long)(n * 128 + o0 + oi)) << 14) + col4;
        #pragma unroll 4
        for (int it = 0; it < 16; ++it) {
            const int i = rgrp + it * 8;
            const float4 t = *(const float4*)(&t4[oi][i][0]);  // broadcast b128
            const float ai = arow[oi][i];
            float4 r;
            r.x = t.x * yr[0][0] + t.y * yr[1][0] + t.z * yr[2][0] + t.w * yr[3][0] + (ai + bj[0]);
            r.y = t.x * yr[0][1] + t.y * yr[1][1] + t.z * yr[2][1] + t.w * yr[3][1] + (ai + bj[1]);
            r.z = t.x * yr[0][2] + t.y * yr[1][2] + t.z * yr[2][2] + t.w * yr[3][2] + (ai + bj[2]);
            r.w = t.x * yr[0][3] + t.y * yr[1][3] + t.z * yr[2][3] + t.w * yr[3][3] + (ai + bj[3]);
            *(float4*)(op + i * 128) = r;                      // dense coalesced store
        }
    }
}

extern "C" void kernel_launch(void* const* d_in, const int* in_sizes, int n_in,
                              void* d_out, int out_size, void* d_ws, size_t ws_size,
                              hipStream_t stream) {
    const float* x    = (const float*)d_in[0];
    const float* y    = (const float*)d_in[1];
    const float* C    = (const float*)d_in[2];
    const float* WA   = (const float*)d_in[3];
    const float* WB   = (const float*)d_in[4];
    const float* bias = (const float*)d_in[5];
    float* out = (float*)d_out;

    scvc_kernel<<<32 * 64, 256, 0, stream>>>(x, y, C, WA, WB, bias, out);
}

// Round 3
// 278.816 us; speedup vs baseline: 1.1847x; 1.1847x over previous
//
#include <hip/hip_runtime.h>

// SCVC: out[n,o,i,j] = sum_{c,d} x[n,c,i] y[n,d,j] Cr[o,c,d]
//                      + a[n,o,i] + b[n,o,j] + bias[o]
// a = dilated conv (k=2, pad=1, dil=2) of channel-tiled x, W_A folded over the
// tile-repeat; b likewise for y / W_B.
// N=32, IN1=IN2=4, OUT=128, DX=DY=128. All float32.
//
// Store-bandwidth-bound: 256 MB out vs ~400 KB in. Phase 2 is laid out so each
// wave store instruction covers 2 full adjacent rows (1 KB, 100% dense).
//
// R3 == R2 intent (266us baseline + nontemporal stores), fixing the compile
// error: __builtin_nontemporal_store needs a native clang vector type, not
// HIP_vector_type<float,4>. Use ext_vector_type(4) alias (same layout/instr).

typedef float f4 __attribute__((ext_vector_type(4)));

__global__ __launch_bounds__(256) void scvc_kernel(
    const float* __restrict__ x,     // [32,4,128]
    const float* __restrict__ y,     // [32,4,128]
    const float* __restrict__ C,     // [128,16]
    const float* __restrict__ WA,    // [128,16,2]
    const float* __restrict__ WB,    // [128,16,2]
    const float* __restrict__ bias,  // [128]
    float* __restrict__ out)         // [32,128,128,128]
{
    const int n   = blockIdx.x >> 7;    // 0..31
    const int o   = blockIdx.x & 127;   // 0..127
    const int tid = threadIdx.x;

    __shared__ float csh[16];       // Cr[c*4+d]
    __shared__ float wash[8];       // folded W_A: [c*2+k]
    __shared__ float wbsh[8];       // folded W_B: [c*2+k]
    __shared__ float t4[128][4];    // t4[i][d] = sum_c x[c,i]*Cr[c,d]
    __shared__ float arow[128];
    __shared__ float bcol[128];     // includes bias

    const float* xb = x + n * 512;
    const float* yb = y + n * 512;

    // ---- phase 0: fold weights into LDS (32 threads) ----
    if (tid < 16) {
        csh[tid] = C[o * 16 + tid];
    } else if (tid < 24) {
        const int idx = tid - 16;           // c*2 + k
        const int c = idx >> 1, k = idx & 1;
        float s = 0.f;
        #pragma unroll
        for (int r = 0; r < 4; ++r) s += WA[o * 32 + (4 * r + c) * 2 + k];
        wash[idx] = s;
    } else if (tid < 32) {
        const int idx = tid - 24;
        const int c = idx >> 1, k = idx & 1;
        float s = 0.f;
        #pragma unroll
        for (int r = 0; r < 4; ++r) s += WB[o * 32 + (4 * r + c) * 2 + k];
        wbsh[idx] = s;
    }
    __syncthreads();

    // ---- phase 1: per-row t4 & arow (threads 0..127), per-col bcol (128..255) ----
    if (tid < 128) {
        const int i = tid;
        float xv[4], xm[4], xp[4];
        #pragma unroll
        for (int c = 0; c < 4; ++c) {
            xv[c] = xb[c * 128 + i];
            xm[c] = (i > 0)   ? xb[c * 128 + i - 1] : 0.f;  // conv tap t-1
            xp[c] = (i < 127) ? xb[c * 128 + i + 1] : 0.f;  // conv tap t+1
        }
        #pragma unroll
        for (int d = 0; d < 4; ++d) {
            float s = 0.f;
            #pragma unroll
            for (int c = 0; c < 4; ++c) s += xv[c] * csh[c * 4 + d];
            t4[i][d] = s;
        }
        float a = 0.f;
        #pragma unroll
        for (int c = 0; c < 4; ++c)
            a += xm[c] * wash[c * 2] + xp[c] * wash[c * 2 + 1];
        arow[i] = a;
    } else {
        const int j = tid - 128;
        float b = bias[o];
        #pragma unroll
        for (int c = 0; c < 4; ++c) {
            float ym = (j > 0)   ? yb[c * 128 + j - 1] : 0.f;
            float yp = (j < 127) ? yb[c * 128 + j + 1] : 0.f;
            b += ym * wbsh[c * 2] + yp * wbsh[c * 2 + 1];
        }
        bcol[j] = b;
    }
    __syncthreads();

    // ---- phase 2: thread owns 4 consecutive cols; 32 threads cover a row.
    // Wave = 2 adjacent rows per store instr -> fully dense 1 KB stores.
    const int col4 = (tid & 31) * 4;   // 0,4,...,124
    const int rgrp = tid >> 5;         // 0..7

    float yr[4][4];
    #pragma unroll
    for (int d = 0; d < 4; ++d) {
        const float4 v = *(const float4*)(yb + d * 128 + col4);
        yr[d][0] = v.x; yr[d][1] = v.y; yr[d][2] = v.z; yr[d][3] = v.w;
    }
    float bj[4];
    #pragma unroll
    for (int jj = 0; jj < 4; ++jj) bj[jj] = bcol[col4 + jj];

    float* op = out + ((long)blockIdx.x << 14) + col4;  // [n,o] tile base
    #pragma unroll
    for (int it = 0; it < 16; ++it) {
        const int i = rgrp + it * 8;
        const float4 t = *(const float4*)(&t4[i][0]);   // broadcast ds_read_b128
        const float ai = arow[i];
        f4 r;
        r.x = t.x * yr[0][0] + t.y * yr[1][0] + t.z * yr[2][0] + t.w * yr[3][0] + (ai + bj[0]);
        r.y = t.x * yr[0][1] + t.y * yr[1][1] + t.z * yr[2][1] + t.w * yr[3][1] + (ai + bj[1]);
        r.z = t.x * yr[0][2] + t.y * yr[1][2] + t.z * yr[2][2] + t.w * yr[3][2] + (ai + bj[2]);
        r.w = t.x * yr[0][3] + t.y * yr[1][3] + t.z * yr[2][3] + t.w * yr[3][3] + (ai + bj[3]);
        // nontemporal: out is written once, never read -> skip L2 allocate
        __builtin_nontemporal_store(r, (f4*)(op + i * 128));
    }
}

extern "C" void kernel_launch(void* const* d_in, const int* in_sizes, int n_in,
                              void* d_out, int out_size, void* d_ws, size_t ws_size,
                              hipStream_t stream) {
    const float* x    = (const float*)d_in[0];
    const float* y    = (const float*)d_in[1];
    const float* C    = (const float*)d_in[2];
    const float* WA   = (const float*)d_in[3];
    const float* WB   = (const float*)d_in[4];
    const float* bias = (const float*)d_in[5];
    float* out = (float*)d_out;

    scvc_kernel<<<32 * 128, 256, 0, stream>>>(x, y, C, WA, WB, bias, out);
}

// Round 4
// 264.749 us; speedup vs baseline: 1.2477x; 1.0531x over previous
//
#include <hip/hip_runtime.h>

// SCVC: out[n,o,i,j] = sum_{c,d} x[n,c,i] y[n,d,j] Cr[o,c,d]
//                      + a[n,o,i] + b[n,o,j] + bias[o]
// a = dilated conv (k=2, pad=1, dil=2) of channel-tiled x, W_A folded over the
// tile-repeat; b likewise for y / W_B.
// N=32, IN1=IN2=4, OUT=128, DX=DY=128. All float32.
//
// Store-bandwidth-bound: 256 MB out vs ~400 KB in. Phase 2 stores: each wave
// instr covers 2 full adjacent rows (1 KB, 100% dense).
//
// R4: controlled re-test of the R1 o-pair structure with the three suspects
// removed: (a) NO __launch_bounds__ min-waves clamp (R1's possible spill
// cause), (b) FULL unroll of the store loop (R1 had unroll 4; R0's known-good
// codegen was full), (c) plain stores (R3 showed nt costs ~+7us).
// Grid 2048 = one (n, o-pair) per block: half the prologues of R0, x/y loads
// and the yr register tile shared across both o values.

__global__ __launch_bounds__(256) void scvc_kernel(
    const float* __restrict__ x,     // [32,4,128]
    const float* __restrict__ y,     // [32,4,128]
    const float* __restrict__ C,     // [128,16]
    const float* __restrict__ WA,    // [128,16,2]
    const float* __restrict__ WB,    // [128,16,2]
    const float* __restrict__ bias,  // [128]
    float* __restrict__ out)         // [32,128,128,128]
{
    const int n   = blockIdx.x >> 6;    // 0..31
    const int og  = blockIdx.x & 63;    // 0..63
    const int o0  = og << 1;            // first of the o-pair
    const int tid = threadIdx.x;

    __shared__ float csh[2][16];        // Cr[c*4+d] per oi
    __shared__ float wash[2][8];        // folded W_A: [c*2+k]
    __shared__ float wbsh[2][8];        // folded W_B: [c*2+k]
    __shared__ float t4[2][128][4];     // t4[oi][i][d] = sum_c x[c,i]*Cr[c,d]
    __shared__ float arow[2][128];
    __shared__ float bcol[2][128];      // includes bias

    const float* xb = x + n * 512;
    const float* yb = y + n * 512;

    // ---- phase 0: fold weights into LDS (64 threads, 32 per o) ----
    if (tid < 64) {
        const int oi = tid >> 5;        // which o of the pair
        const int o  = o0 + oi;
        const int t  = tid & 31;
        if (t < 16) {
            csh[oi][t] = C[o * 16 + t];
        } else if (t < 24) {
            const int idx = t - 16;             // c*2 + k
            const int c = idx >> 1, k = idx & 1;
            float s = 0.f;
            #pragma unroll
            for (int r = 0; r < 4; ++r) s += WA[o * 32 + (4 * r + c) * 2 + k];
            wash[oi][idx] = s;
        } else {
            const int idx = t - 24;
            const int c = idx >> 1, k = idx & 1;
            float s = 0.f;
            #pragma unroll
            for (int r = 0; r < 4; ++r) s += WB[o * 32 + (4 * r + c) * 2 + k];
            wbsh[oi][idx] = s;
        }
    }
    __syncthreads();

    // ---- phase 1: rows (threads 0..127) / cols (128..255), both o's ----
    if (tid < 128) {
        const int i = tid;
        float xv[4], xm[4], xp[4];
        #pragma unroll
        for (int c = 0; c < 4; ++c) {
            xv[c] = xb[c * 128 + i];
            xm[c] = (i > 0)   ? xb[c * 128 + i - 1] : 0.f;  // conv tap t-1
            xp[c] = (i < 127) ? xb[c * 128 + i + 1] : 0.f;  // conv tap t+1
        }
        #pragma unroll
        for (int oi = 0; oi < 2; ++oi) {
            #pragma unroll
            for (int d = 0; d < 4; ++d) {
                float s = 0.f;
                #pragma unroll
                for (int c = 0; c < 4; ++c) s += xv[c] * csh[oi][c * 4 + d];
                t4[oi][i][d] = s;
            }
            float a = 0.f;
            #pragma unroll
            for (int c = 0; c < 4; ++c)
                a += xm[c] * wash[oi][c * 2] + xp[c] * wash[oi][c * 2 + 1];
            arow[oi][i] = a;
        }
    } else {
        const int j = tid - 128;
        float ym[4], yp[4];
        #pragma unroll
        for (int c = 0; c < 4; ++c) {
            ym[c] = (j > 0)   ? yb[c * 128 + j - 1] : 0.f;
            yp[c] = (j < 127) ? yb[c * 128 + j + 1] : 0.f;
        }
        #pragma unroll
        for (int oi = 0; oi < 2; ++oi) {
            float b = bias[o0 + oi];
            #pragma unroll
            for (int c = 0; c < 4; ++c)
                b += ym[c] * wbsh[oi][c * 2] + yp[c] * wbsh[oi][c * 2 + 1];
            bcol[oi][j] = b;
        }
    }
    __syncthreads();

    // ---- phase 2: thread owns 4 consecutive cols; 32 threads cover a row.
    // Wave = 2 adjacent rows per store instr -> fully dense 1 KB stores.
    // Both o's of the pair streamed back-to-back, reusing yr registers.
    const int col4 = (tid & 31) * 4;   // 0,4,...,124
    const int rgrp = tid >> 5;         // 0..7

    float yr[4][4];
    #pragma unroll
    for (int d = 0; d < 4; ++d) {
        const float4 v = *(const float4*)(yb + d * 128 + col4);
        yr[d][0] = v.x; yr[d][1] = v.y; yr[d][2] = v.z; yr[d][3] = v.w;
    }

    #pragma unroll
    for (int oi = 0; oi < 2; ++oi) {
        const float4 bv = *(const float4*)(&bcol[oi][col4]);  // one ds_read_b128
        float bj[4];
        bj[0] = bv.x; bj[1] = bv.y; bj[2] = bv.z; bj[3] = bv.w;

        float* op = out + (((long)(n * 128 + o0 + oi)) << 14) + col4;
        #pragma unroll
        for (int it = 0; it < 16; ++it) {
            const int i = rgrp + it * 8;
            const float4 t = *(const float4*)(&t4[oi][i][0]);  // broadcast b128
            const float ai = arow[oi][i];
            float4 r;
            r.x = t.x * yr[0][0] + t.y * yr[1][0] + t.z * yr[2][0] + t.w * yr[3][0] + (ai + bj[0]);
            r.y = t.x * yr[0][1] + t.y * yr[1][1] + t.z * yr[2][1] + t.w * yr[3][1] + (ai + bj[1]);
            r.z = t.x * yr[0][2] + t.y * yr[1][2] + t.z * yr[2][2] + t.w * yr[3][2] + (ai + bj[2]);
            r.w = t.x * yr[0][3] + t.y * yr[1][3] + t.z * yr[2][3] + t.w * yr[3][3] + (ai + bj[3]);
            *(float4*)(op + i * 128) = r;                      // dense coalesced store
        }
    }
}

extern "C" void kernel_launch(void* const* d_in, const int* in_sizes, int n_in,
                              void* d_out, int out_size, void* d_ws, size_t ws_size,
                              hipStream_t stream) {
    const float* x    = (const float*)d_in[0];
    const float* y    = (const float*)d_in[1];
    const float* C    = (const float*)d_in[2];
    const float* WA   = (const float*)d_in[3];
    const float* WB   = (const float*)d_in[4];
    const float* bias = (const float*)d_in[5];
    float* out = (float*)d_out;

    scvc_kernel<<<32 * 64, 256, 0, stream>>>(x, y, C, WA, WB, bias, out);
}

// Round 5
// 263.061 us; speedup vs baseline: 1.2557x; 1.0064x over previous
//
#include <hip/hip_runtime.h>

// SCVC: out[n,o,i,j] = sum_{c,d} x[n,c,i] y[n,d,j] Cr[o,c,d]
//                      + a[n,o,i] + b[n,o,j] + bias[o]
// a = dilated conv (k=2, pad=1, dil=2) of channel-tiled x, W_A folded over the
// tile-repeat; b likewise for y / W_B.
// N=32, IN1=IN2=4, OUT=128, DX=DY=128. All float32.
//
// Store-bandwidth-bound: 256 MB out vs ~400 KB in.
// Ledger: R0 base 266.4 | R1 o-pair+clamp+unroll4 regressed (clamp artifact) |
// R3 nontemporal stores +7us (reverted) | R4 o-pair clean = 264.7 (neutral ->
// prologues fully hidden; kernel part ~100us vs ~41us fill-rate floor).
//
// R5 single change on the R4 base: per-wave LINEAR store streams. Before:
// wave w stored row pairs {8it+2w, 8it+2w+1} -> 1KB chunks strided 4KB.
// Now: wave w owns rows [32w, 32w+32) and marches sequentially -> each wave
// issues a contiguous 32KB linear store stream per o (fill-like), testing
// whether the write path rewards per-wave linearity.

__global__ __launch_bounds__(256) void scvc_kernel(
    const float* __restrict__ x,     // [32,4,128]
    const float* __restrict__ y,     // [32,4,128]
    const float* __restrict__ C,     // [128,16]
    const float* __restrict__ WA,    // [128,16,2]
    const float* __restrict__ WB,    // [128,16,2]
    const float* __restrict__ bias,  // [128]
    float* __restrict__ out)         // [32,128,128,128]
{
    const int n   = blockIdx.x >> 6;    // 0..31
    const int og  = blockIdx.x & 63;    // 0..63
    const int o0  = og << 1;            // first of the o-pair
    const int tid = threadIdx.x;

    __shared__ float csh[2][16];        // Cr[c*4+d] per oi
    __shared__ float wash[2][8];        // folded W_A: [c*2+k]
    __shared__ float wbsh[2][8];        // folded W_B: [c*2+k]
    __shared__ float t4[2][128][4];     // t4[oi][i][d] = sum_c x[c,i]*Cr[c,d]
    __shared__ float arow[2][128];
    __shared__ float bcol[2][128];      // includes bias

    const float* xb = x + n * 512;
    const float* yb = y + n * 512;

    // ---- phase 0: fold weights into LDS (64 threads, 32 per o) ----
    if (tid < 64) {
        const int oi = tid >> 5;        // which o of the pair
        const int o  = o0 + oi;
        const int t  = tid & 31;
        if (t < 16) {
            csh[oi][t] = C[o * 16 + t];
        } else if (t < 24) {
            const int idx = t - 16;             // c*2 + k
            const int c = idx >> 1, k = idx & 1;
            float s = 0.f;
            #pragma unroll
            for (int r = 0; r < 4; ++r) s += WA[o * 32 + (4 * r + c) * 2 + k];
            wash[oi][idx] = s;
        } else {
            const int idx = t - 24;
            const int c = idx >> 1, k = idx & 1;
            float s = 0.f;
            #pragma unroll
            for (int r = 0; r < 4; ++r) s += WB[o * 32 + (4 * r + c) * 2 + k];
            wbsh[oi][idx] = s;
        }
    }
    __syncthreads();

    // ---- phase 1: rows (threads 0..127) / cols (128..255), both o's ----
    if (tid < 128) {
        const int i = tid;
        float xv[4], xm[4], xp[4];
        #pragma unroll
        for (int c = 0; c < 4; ++c) {
            xv[c] = xb[c * 128 + i];
            xm[c] = (i > 0)   ? xb[c * 128 + i - 1] : 0.f;  // conv tap t-1
            xp[c] = (i < 127) ? xb[c * 128 + i + 1] : 0.f;  // conv tap t+1
        }
        #pragma unroll
        for (int oi = 0; oi < 2; ++oi) {
            #pragma unroll
            for (int d = 0; d < 4; ++d) {
                float s = 0.f;
                #pragma unroll
                for (int c = 0; c < 4; ++c) s += xv[c] * csh[oi][c * 4 + d];
                t4[oi][i][d] = s;
            }
            float a = 0.f;
            #pragma unroll
            for (int c = 0; c < 4; ++c)
                a += xm[c] * wash[oi][c * 2] + xp[c] * wash[oi][c * 2 + 1];
            arow[oi][i] = a;
        }
    } else {
        const int j = tid - 128;
        float ym[4], yp[4];
        #pragma unroll
        for (int c = 0; c < 4; ++c) {
            ym[c] = (j > 0)   ? yb[c * 128 + j - 1] : 0.f;
            yp[c] = (j < 127) ? yb[c * 128 + j + 1] : 0.f;
        }
        #pragma unroll
        for (int oi = 0; oi < 2; ++oi) {
            float b = bias[o0 + oi];
            #pragma unroll
            for (int c = 0; c < 4; ++c)
                b += ym[c] * wbsh[oi][c * 2] + yp[c] * wbsh[oi][c * 2 + 1];
            bcol[oi][j] = b;
        }
    }
    __syncthreads();

    // ---- phase 2: per-wave LINEAR streams. Wave w owns rows [32w, 32w+32).
    // Each store instr: lanes 0-31 -> row (32w + 2it), lanes 32-63 -> row
    // (32w + 2it + 1) = one dense 1KB line; successive it's are sequential
    // addresses -> each wave emits a contiguous 32KB linear stream per o.
    const int wave = tid >> 6;          // 0..3
    const int lane = tid & 63;
    const int col4 = (lane & 31) * 4;   // 0,4,...,124
    const int half = lane >> 5;         // 0/1

    float yr[4][4];
    #pragma unroll
    for (int d = 0; d < 4; ++d) {
        const float4 v = *(const float4*)(yb + d * 128 + col4);
        yr[d][0] = v.x; yr[d][1] = v.y; yr[d][2] = v.z; yr[d][3] = v.w;
    }

    #pragma unroll
    for (int oi = 0; oi < 2; ++oi) {
        const float4 bv = *(const float4*)(&bcol[oi][col4]);  // broadcast-pair read
        float bj[4];
        bj[0] = bv.x; bj[1] = bv.y; bj[2] = bv.z; bj[3] = bv.w;

        float* op = out + (((long)(n * 128 + o0 + oi)) << 14) + col4;
        #pragma unroll
        for (int it = 0; it < 16; ++it) {
            const int i = wave * 32 + it * 2 + half;
            const float4 t = *(const float4*)(&t4[oi][i][0]);  // broadcast b128
            const float ai = arow[oi][i];
            float4 r;
            r.x = t.x * yr[0][0] + t.y * yr[1][0] + t.z * yr[2][0] + t.w * yr[3][0] + (ai + bj[0]);
            r.y = t.x * yr[0][1] + t.y * yr[1][1] + t.z * yr[2][1] + t.w * yr[3][1] + (ai + bj[1]);
            r.z = t.x * yr[0][2] + t.y * yr[1][2] + t.z * yr[2][2] + t.w * yr[3][2] + (ai + bj[2]);
            r.w = t.x * yr[0][3] + t.y * yr[1][3] + t.z * yr[2][3] + t.w * yr[3][3] + (ai + bj[3]);
            *(float4*)(op + i * 128) = r;                      // dense, linear per wave
        }
    }
}

extern "C" void kernel_launch(void* const* d_in, const int* in_sizes, int n_in,
                              void* d_out, int out_size, void* d_ws, size_t ws_size,
                              hipStream_t stream) {
    const float* x    = (const float*)d_in[0];
    const float* y    = (const float*)d_in[1];
    const float* C    = (const float*)d_in[2];
    const float* WA   = (const float*)d_in[3];
    const float* WB   = (const float*)d_in[4];
    const float* bias = (const float*)d_in[5];
    float* out = (float*)d_out;

    scvc_kernel<<<32 * 64, 256, 0, stream>>>(x, y, C, WA, WB, bias, out);
}